// Round 4
// baseline (57.563 us; speedup 1.0000x reference)
//
#include <hip/hip_runtime.h>

// FrequencyLayer: 8x8 patch DCT-II, keep 2x2 low corner and flipped 2x2 high corner.
// x: (64,3,512,512) f32. Outputs: low||high, each (64,64,64,3,2,2) f32.
//
// Output linear index: b*49152 + ss*768 + tt*12 + rr*4 + k*2 + l
// where the source patch is m = rr*4096 + ss*64 + tt, and m = p*192 + q*3 + c.
//
// Block = (b, ss): 192 threads, one patch each (rr = idx>>6, tt = idx&63).
// Results staged in LDS in output order -> two contiguous 3 KB float4 bursts.
//
// R4 = R3 with the nontemporal stores through clang native vector type
// (ext_vector_type) — __builtin_nontemporal_store rejects HIP_vector_type*.

typedef float floatx4 __attribute__((ext_vector_type(4)));

__global__ __launch_bounds__(192, 6) void freq_dct_kernel(
    const float* __restrict__ x, float* __restrict__ out_low, float* __restrict__ out_high)
{
    // DCT-II rows 0,1,6,7 (scaled): DR[0]=row0, DR[1]=row1, DR[2]=row6, DR[3]=row7
    const float DR[4][8] = {
        { 0.35355339059327373f, 0.35355339059327373f, 0.35355339059327373f, 0.35355339059327373f,
          0.35355339059327373f, 0.35355339059327373f, 0.35355339059327373f, 0.35355339059327373f },
        { 0.49039264020161522f, 0.41573480615127262f, 0.27778511650980109f, 0.09754516100806412f,
         -0.09754516100806412f,-0.27778511650980109f,-0.41573480615127262f,-0.49039264020161522f },
        { 0.19134171618254489f,-0.46193976625564337f, 0.46193976625564337f,-0.19134171618254489f,
         -0.19134171618254489f, 0.46193976625564337f,-0.46193976625564337f, 0.19134171618254489f },
        { 0.09754516100806412f,-0.27778511650980109f, 0.41573480615127262f,-0.49039264020161522f,
          0.49039264020161522f,-0.41573480615127262f, 0.27778511650980109f,-0.09754516100806412f }
    };

    __shared__ float lds_lo[768];
    __shared__ float lds_hi[768];

    const int bss = blockIdx.x;        // b*64 + ss
    const int b   = bss >> 6;
    const int ss  = bss & 63;
    const int idx = threadIdx.x;       // 0..191
    const int rr  = idx >> 6;          // wave id (0..2)
    const int tt  = idx & 63;          // lane

    // Patch for this output slot
    const int m   = rr * 4096 + ss * 64 + tt;
    const int p   = m / 192;
    const int rem = m - p * 192;
    const int q   = rem / 3;
    const int c   = rem - q * 3;

    const float* src = x + ((size_t)(b * 3 + c) * 512 + (size_t)p * 8) * 512 + (size_t)q * 8;

    // Row-wise accumulation: per row i, u[l] = sum_j x[i][j]*DR[l][j], then
    // lv[a*2+l] += DR[a][i]*u[l];  hv[a*2+l] += DR[3-a][i]*u[3-l].
    float lv[4] = {0.f, 0.f, 0.f, 0.f};
    float hv[4] = {0.f, 0.f, 0.f, 0.f};

    #pragma unroll
    for (int i = 0; i < 8; ++i) {
        const float4 a0 = *reinterpret_cast<const float4*>(src + (size_t)i * 512);
        const float4 a1 = *reinterpret_cast<const float4*>(src + (size_t)i * 512 + 4);
        const float row[8] = { a0.x, a0.y, a0.z, a0.w, a1.x, a1.y, a1.z, a1.w };

        float u[4] = {0.f, 0.f, 0.f, 0.f};
        #pragma unroll
        for (int j = 0; j < 8; ++j) {
            #pragma unroll
            for (int l = 0; l < 4; ++l) u[l] = fmaf(row[j], DR[l][j], u[l]);
        }
        #pragma unroll
        for (int a = 0; a < 2; ++a) {
            const float dl = DR[a][i];
            const float dh = DR[3 - a][i];
            #pragma unroll
            for (int l = 0; l < 2; ++l) {
                lv[a * 2 + l] = fmaf(dl, u[l],     lv[a * 2 + l]);
                hv[a * 2 + l] = fmaf(dh, u[3 - l], hv[a * 2 + l]);
            }
        }
    }

    // Stage results in LDS in output order: [tt][rr][e]
    const int base = tt * 12 + rr * 4;    // 16-B aligned
    *reinterpret_cast<float4*>(&lds_lo[base]) = make_float4(lv[0], lv[1], lv[2], lv[3]);
    *reinterpret_cast<float4*>(&lds_hi[base]) = make_float4(hv[0], hv[1], hv[2], hv[3]);
    __syncthreads();

    // Cooperative contiguous write: 192 threads x float4 = 3 KB per output per block.
    // Nontemporal: outputs are never re-read; don't pollute L2.
    const size_t off = (size_t)bss * 768 + (size_t)idx * 4;
    const floatx4 lo4 = *reinterpret_cast<const floatx4*>(&lds_lo[idx * 4]);
    const floatx4 hi4 = *reinterpret_cast<const floatx4*>(&lds_hi[idx * 4]);
    __builtin_nontemporal_store(lo4, reinterpret_cast<floatx4*>(out_low  + off));
    __builtin_nontemporal_store(hi4, reinterpret_cast<floatx4*>(out_high + off));
}

extern "C" void kernel_launch(void* const* d_in, const int* in_sizes, int n_in,
                              void* d_out, int out_size, void* d_ws, size_t ws_size,
                              hipStream_t stream) {
    const float* x = (const float*)d_in[0];
    float* out  = (float*)d_out;
    float* low  = out;
    float* high = out + 3145728;   // 64*64*64*3*2*2

    // 64 b * 64 ss = 4096 blocks, 192 threads each (one patch per thread)
    hipLaunchKernelGGL(freq_dct_kernel, dim3(4096), dim3(192), 0, stream,
                       x, low, high);
}

// Round 5
// 42.987 us; speedup vs baseline: 1.3391x; 1.3391x over previous
//
#include <hip/hip_runtime.h>

// FrequencyLayer: 8x8 patch DCT-II, keep 2x2 low corner and flipped 2x2 high corner.
// x: (64,3,512,512) f32. Outputs: low||high, each (64,64,64,3,2,2) f32.
//
// Output linear index: b*49152 + ss*768 + tt*12 + rr*4 + k*2 + l
// where the source patch is m = rr*4096 + ss*64 + tt, and m = p*192 + q*3 + c.
//
// Block = (b, ss): 192 threads, one patch each (rr = idx>>6, tt = idx&63).
// Results staged in LDS in output order -> two contiguous 3 KB float4 bursts.
//
// R5 = exact R2 structure (43.3 us known-good) + ONE change: nontemporal
// stores (clean A/B; R4 bundled three changes and regressed, suspect was
// __launch_bounds__(192,6) register capping -> spills).

typedef float floatx4 __attribute__((ext_vector_type(4)));

__global__ __launch_bounds__(192) void freq_dct_kernel(
    const float* __restrict__ x, float* __restrict__ out_low, float* __restrict__ out_high)
{
    // DCT-II rows 0,1,6,7 (scaled): DR[0]=row0, DR[1]=row1, DR[2]=row6, DR[3]=row7
    const float DR[4][8] = {
        { 0.35355339059327373f, 0.35355339059327373f, 0.35355339059327373f, 0.35355339059327373f,
          0.35355339059327373f, 0.35355339059327373f, 0.35355339059327373f, 0.35355339059327373f },
        { 0.49039264020161522f, 0.41573480615127262f, 0.27778511650980109f, 0.09754516100806412f,
         -0.09754516100806412f,-0.27778511650980109f,-0.41573480615127262f,-0.49039264020161522f },
        { 0.19134171618254489f,-0.46193976625564337f, 0.46193976625564337f,-0.19134171618254489f,
         -0.19134171618254489f, 0.46193976625564337f,-0.46193976625564337f, 0.19134171618254489f },
        { 0.09754516100806412f,-0.27778511650980109f, 0.41573480615127262f,-0.49039264020161522f,
          0.49039264020161522f,-0.41573480615127262f, 0.27778511650980109f,-0.09754516100806412f }
    };

    __shared__ float lds_lo[768];
    __shared__ float lds_hi[768];

    const int bss = blockIdx.x;        // b*64 + ss
    const int b   = bss >> 6;
    const int ss  = bss & 63;
    const int idx = threadIdx.x;       // 0..191
    const int rr  = idx >> 6;          // wave id (0..2)
    const int tt  = idx & 63;          // lane

    // Patch for this output slot
    const int m   = rr * 4096 + ss * 64 + tt;
    const int p   = m / 192;
    const int rem = m - p * 192;
    const int q   = rem / 3;
    const int c   = rem - q * 3;

    const float* src = x + ((size_t)(b * 3 + c) * 512 + (size_t)p * 8) * 512 + (size_t)q * 8;

    // Stage 1: t[k][j] = sum_i DR[k][i] * patch[i][j]
    float t[4][8];
    #pragma unroll
    for (int k = 0; k < 4; ++k)
        #pragma unroll
        for (int j = 0; j < 8; ++j) t[k][j] = 0.0f;

    #pragma unroll
    for (int i = 0; i < 8; ++i) {
        const float4 a0 = *reinterpret_cast<const float4*>(src + (size_t)i * 512);
        const float4 a1 = *reinterpret_cast<const float4*>(src + (size_t)i * 512 + 4);
        const float row[8] = { a0.x, a0.y, a0.z, a0.w, a1.x, a1.y, a1.z, a1.w };
        #pragma unroll
        for (int k = 0; k < 4; ++k) {
            const float dk = DR[k][i];
            #pragma unroll
            for (int j = 0; j < 8; ++j) t[k][j] = fmaf(dk, row[j], t[k][j]);
        }
    }

    // Stage 2: d[k][l] = sum_j t[k][j] * DR_l[j];  low = d[a][l], high = d[7-a][7-l]
    float lv[4], hv[4];
    #pragma unroll
    for (int a = 0; a < 2; ++a) {
        #pragma unroll
        for (int l = 0; l < 2; ++l) {
            float accL = 0.0f, accH = 0.0f;
            #pragma unroll
            for (int j = 0; j < 8; ++j) {
                accL = fmaf(t[a][j],     DR[l][j],     accL);
                accH = fmaf(t[3 - a][j], DR[3 - l][j], accH);
            }
            lv[a * 2 + l] = accL;
            hv[a * 2 + l] = accH;
        }
    }

    // Stage results in LDS in output order: [tt][rr][e]
    const int base = tt * 12 + rr * 4;    // 16-B aligned
    *reinterpret_cast<float4*>(&lds_lo[base]) = make_float4(lv[0], lv[1], lv[2], lv[3]);
    *reinterpret_cast<float4*>(&lds_hi[base]) = make_float4(hv[0], hv[1], hv[2], hv[3]);
    __syncthreads();

    // Cooperative contiguous write: 192 threads x float4 = 3 KB per output per block.
    // Nontemporal: outputs are never re-read; keep L2/L3 for the read stream.
    const size_t off = (size_t)bss * 768 + (size_t)idx * 4;
    const floatx4 lo4 = *reinterpret_cast<const floatx4*>(&lds_lo[idx * 4]);
    const floatx4 hi4 = *reinterpret_cast<const floatx4*>(&lds_hi[idx * 4]);
    __builtin_nontemporal_store(lo4, reinterpret_cast<floatx4*>(out_low  + off));
    __builtin_nontemporal_store(hi4, reinterpret_cast<floatx4*>(out_high + off));
}

extern "C" void kernel_launch(void* const* d_in, const int* in_sizes, int n_in,
                              void* d_out, int out_size, void* d_ws, size_t ws_size,
                              hipStream_t stream) {
    const float* x = (const float*)d_in[0];
    float* out  = (float*)d_out;
    float* low  = out;
    float* high = out + 3145728;   // 64*64*64*3*2*2

    // 64 b * 64 ss = 4096 blocks, 192 threads each (one patch per thread)
    hipLaunchKernelGGL(freq_dct_kernel, dim3(4096), dim3(192), 0, stream,
                       x, low, high);
}

// Round 6
// 39.934 us; speedup vs baseline: 1.4415x; 1.0765x over previous
//
#include <hip/hip_runtime.h>

// FrequencyLayer: 8x8 patch DCT-II, keep 2x2 low corner and flipped 2x2 high corner.
// x: (64,3,512,512) f32. Outputs: low||high, each (64,64,64,3,2,2) f32.
//
// Output linear index: b*49152 + ss*768 + tt*12 + rr*4 + k*2 + l
// where the source patch is m = rr*4096 + ss*64 + tt, and m = p*192 + q*3 + c.
//
// Block = (b, ss): 192 threads, one patch each (rr = idx>>6, tt = idx&63).
// Results staged in LDS in output order -> two contiguous 3 KB float4 bursts.
//
// R6 = R5 (43.0 us) + ONE change: row-wise accumulation (u[4] per row) to cut
// live registers ~32 -> ~12, raising NATURAL occupancy (no min-waves cap —
// R4's forced (192,6) cap caused spills and +14 us).

typedef float floatx4 __attribute__((ext_vector_type(4)));

__global__ __launch_bounds__(192) void freq_dct_kernel(
    const float* __restrict__ x, float* __restrict__ out_low, float* __restrict__ out_high)
{
    // DCT-II rows 0,1,6,7 (scaled): DR[0]=row0, DR[1]=row1, DR[2]=row6, DR[3]=row7
    const float DR[4][8] = {
        { 0.35355339059327373f, 0.35355339059327373f, 0.35355339059327373f, 0.35355339059327373f,
          0.35355339059327373f, 0.35355339059327373f, 0.35355339059327373f, 0.35355339059327373f },
        { 0.49039264020161522f, 0.41573480615127262f, 0.27778511650980109f, 0.09754516100806412f,
         -0.09754516100806412f,-0.27778511650980109f,-0.41573480615127262f,-0.49039264020161522f },
        { 0.19134171618254489f,-0.46193976625564337f, 0.46193976625564337f,-0.19134171618254489f,
         -0.19134171618254489f, 0.46193976625564337f,-0.46193976625564337f, 0.19134171618254489f },
        { 0.09754516100806412f,-0.27778511650980109f, 0.41573480615127262f,-0.49039264020161522f,
          0.49039264020161522f,-0.41573480615127262f, 0.27778511650980109f,-0.09754516100806412f }
    };

    __shared__ float lds_lo[768];
    __shared__ float lds_hi[768];

    const int bss = blockIdx.x;        // b*64 + ss
    const int b   = bss >> 6;
    const int ss  = bss & 63;
    const int idx = threadIdx.x;       // 0..191
    const int rr  = idx >> 6;          // wave id (0..2)
    const int tt  = idx & 63;          // lane

    // Patch for this output slot
    const int m   = rr * 4096 + ss * 64 + tt;
    const int p   = m / 192;
    const int rem = m - p * 192;
    const int q   = rem / 3;
    const int c   = rem - q * 3;

    const float* src = x + ((size_t)(b * 3 + c) * 512 + (size_t)p * 8) * 512 + (size_t)q * 8;

    // Row-wise accumulation: per row i, u[l] = sum_j x[i][j]*DR[l][j], then
    // lv[a*2+l] += DR[a][i]*u[l];  hv[a*2+l] += DR[3-a][i]*u[3-l].
    float lv[4] = {0.f, 0.f, 0.f, 0.f};
    float hv[4] = {0.f, 0.f, 0.f, 0.f};

    #pragma unroll
    for (int i = 0; i < 8; ++i) {
        const float4 a0 = *reinterpret_cast<const float4*>(src + (size_t)i * 512);
        const float4 a1 = *reinterpret_cast<const float4*>(src + (size_t)i * 512 + 4);
        const float row[8] = { a0.x, a0.y, a0.z, a0.w, a1.x, a1.y, a1.z, a1.w };

        float u[4] = {0.f, 0.f, 0.f, 0.f};
        #pragma unroll
        for (int j = 0; j < 8; ++j) {
            #pragma unroll
            for (int l = 0; l < 4; ++l) u[l] = fmaf(row[j], DR[l][j], u[l]);
        }
        #pragma unroll
        for (int a = 0; a < 2; ++a) {
            const float dl = DR[a][i];
            const float dh = DR[3 - a][i];
            #pragma unroll
            for (int l = 0; l < 2; ++l) {
                lv[a * 2 + l] = fmaf(dl, u[l],     lv[a * 2 + l]);
                hv[a * 2 + l] = fmaf(dh, u[3 - l], hv[a * 2 + l]);
            }
        }
    }

    // Stage results in LDS in output order: [tt][rr][e]
    const int base = tt * 12 + rr * 4;    // 16-B aligned
    *reinterpret_cast<float4*>(&lds_lo[base]) = make_float4(lv[0], lv[1], lv[2], lv[3]);
    *reinterpret_cast<float4*>(&lds_hi[base]) = make_float4(hv[0], hv[1], hv[2], hv[3]);
    __syncthreads();

    // Cooperative contiguous write: 192 threads x float4 = 3 KB per output per block.
    // Nontemporal: outputs are never re-read; keep L2/L3 for the read stream.
    const size_t off = (size_t)bss * 768 + (size_t)idx * 4;
    const floatx4 lo4 = *reinterpret_cast<const floatx4*>(&lds_lo[idx * 4]);
    const floatx4 hi4 = *reinterpret_cast<const floatx4*>(&lds_hi[idx * 4]);
    __builtin_nontemporal_store(lo4, reinterpret_cast<floatx4*>(out_low  + off));
    __builtin_nontemporal_store(hi4, reinterpret_cast<floatx4*>(out_high + off));
}

extern "C" void kernel_launch(void* const* d_in, const int* in_sizes, int n_in,
                              void* d_out, int out_size, void* d_ws, size_t ws_size,
                              hipStream_t stream) {
    const float* x = (const float*)d_in[0];
    float* out  = (float*)d_out;
    float* low  = out;
    float* high = out + 3145728;   // 64*64*64*3*2*2

    // 64 b * 64 ss = 4096 blocks, 192 threads each (one patch per thread)
    hipLaunchKernelGGL(freq_dct_kernel, dim3(4096), dim3(192), 0, stream,
                       x, low, high);
}

// Round 7
// 39.868 us; speedup vs baseline: 1.4439x; 1.0017x over previous
//
#include <hip/hip_runtime.h>

// FrequencyLayer: 8x8 patch DCT-II, keep 2x2 low corner and flipped 2x2 high corner.
// x: (64,3,512,512) f32. Outputs: low||high, each (64,64,64,3,2,2) f32.
//
// Output linear index: b*49152 + ss*768 + tt*12 + rr*4 + k*2 + l
// where the source patch is m = rr*4096 + ss*64 + tt, and m = p*192 + q*3 + c.
//
// Block = (b, ss): 192 threads, one patch each (rr = idx>>6, tt = idx&63).
// Results staged in LDS in output order -> two contiguous 3 KB float4 bursts.
//
// R7 = R6 (39.9 us) + ONE change: hoist ALL 16 float4 loads before compute
// (max memory-level parallelism per wave; 16 outstanding loads). Static
// array indices under full unroll -> registers, not scratch.

typedef float floatx4 __attribute__((ext_vector_type(4)));

__global__ __launch_bounds__(192) void freq_dct_kernel(
    const float* __restrict__ x, float* __restrict__ out_low, float* __restrict__ out_high)
{
    // DCT-II rows 0,1,6,7 (scaled): DR[0]=row0, DR[1]=row1, DR[2]=row6, DR[3]=row7
    const float DR[4][8] = {
        { 0.35355339059327373f, 0.35355339059327373f, 0.35355339059327373f, 0.35355339059327373f,
          0.35355339059327373f, 0.35355339059327373f, 0.35355339059327373f, 0.35355339059327373f },
        { 0.49039264020161522f, 0.41573480615127262f, 0.27778511650980109f, 0.09754516100806412f,
         -0.09754516100806412f,-0.27778511650980109f,-0.41573480615127262f,-0.49039264020161522f },
        { 0.19134171618254489f,-0.46193976625564337f, 0.46193976625564337f,-0.19134171618254489f,
         -0.19134171618254489f, 0.46193976625564337f,-0.46193976625564337f, 0.19134171618254489f },
        { 0.09754516100806412f,-0.27778511650980109f, 0.41573480615127262f,-0.49039264020161522f,
          0.49039264020161522f,-0.41573480615127262f, 0.27778511650980109f,-0.09754516100806412f }
    };

    __shared__ float lds_lo[768];
    __shared__ float lds_hi[768];

    const int bss = blockIdx.x;        // b*64 + ss
    const int b   = bss >> 6;
    const int ss  = bss & 63;
    const int idx = threadIdx.x;       // 0..191
    const int rr  = idx >> 6;          // wave id (0..2)
    const int tt  = idx & 63;          // lane

    // Patch for this output slot
    const int m   = rr * 4096 + ss * 64 + tt;
    const int p   = m / 192;
    const int rem = m - p * 192;
    const int q   = rem / 3;
    const int c   = rem - q * 3;

    const float* src = x + ((size_t)(b * 3 + c) * 512 + (size_t)p * 8) * 512 + (size_t)q * 8;

    // Hoist all 16 loads: 16 outstanding per lane before any compute.
    float4 A[8], B[8];
    #pragma unroll
    for (int i = 0; i < 8; ++i) {
        A[i] = *reinterpret_cast<const float4*>(src + (size_t)i * 512);
        B[i] = *reinterpret_cast<const float4*>(src + (size_t)i * 512 + 4);
    }

    // Row-wise accumulation: per row i, u[l] = sum_j x[i][j]*DR[l][j], then
    // lv[a*2+l] += DR[a][i]*u[l];  hv[a*2+l] += DR[3-a][i]*u[3-l].
    float lv[4] = {0.f, 0.f, 0.f, 0.f};
    float hv[4] = {0.f, 0.f, 0.f, 0.f};

    #pragma unroll
    for (int i = 0; i < 8; ++i) {
        const float row[8] = { A[i].x, A[i].y, A[i].z, A[i].w,
                               B[i].x, B[i].y, B[i].z, B[i].w };
        float u[4] = {0.f, 0.f, 0.f, 0.f};
        #pragma unroll
        for (int j = 0; j < 8; ++j) {
            #pragma unroll
            for (int l = 0; l < 4; ++l) u[l] = fmaf(row[j], DR[l][j], u[l]);
        }
        #pragma unroll
        for (int a = 0; a < 2; ++a) {
            const float dl = DR[a][i];
            const float dh = DR[3 - a][i];
            #pragma unroll
            for (int l = 0; l < 2; ++l) {
                lv[a * 2 + l] = fmaf(dl, u[l],     lv[a * 2 + l]);
                hv[a * 2 + l] = fmaf(dh, u[3 - l], hv[a * 2 + l]);
            }
        }
    }

    // Stage results in LDS in output order: [tt][rr][e]
    const int base = tt * 12 + rr * 4;    // 16-B aligned
    *reinterpret_cast<float4*>(&lds_lo[base]) = make_float4(lv[0], lv[1], lv[2], lv[3]);
    *reinterpret_cast<float4*>(&lds_hi[base]) = make_float4(hv[0], hv[1], hv[2], hv[3]);
    __syncthreads();

    // Cooperative contiguous write: 192 threads x float4 = 3 KB per output per block.
    // Nontemporal: outputs are never re-read; keep L2/L3 for the read stream.
    const size_t off = (size_t)bss * 768 + (size_t)idx * 4;
    const floatx4 lo4 = *reinterpret_cast<const floatx4*>(&lds_lo[idx * 4]);
    const floatx4 hi4 = *reinterpret_cast<const floatx4*>(&lds_hi[idx * 4]);
    __builtin_nontemporal_store(lo4, reinterpret_cast<floatx4*>(out_low  + off));
    __builtin_nontemporal_store(hi4, reinterpret_cast<floatx4*>(out_high + off));
}

extern "C" void kernel_launch(void* const* d_in, const int* in_sizes, int n_in,
                              void* d_out, int out_size, void* d_ws, size_t ws_size,
                              hipStream_t stream) {
    const float* x = (const float*)d_in[0];
    float* out  = (float*)d_out;
    float* low  = out;
    float* high = out + 3145728;   // 64*64*64*3*2*2

    // 64 b * 64 ss = 4096 blocks, 192 threads each (one patch per thread)
    hipLaunchKernelGGL(freq_dct_kernel, dim3(4096), dim3(192), 0, stream,
                       x, low, high);
}